// Round 6
// baseline (58589.594 us; speedup 1.0000x reference)
//
#include <hip/hip_runtime.h>
#include <stdint.h>

#define NBLK 256
#define NTHR 512

typedef __attribute__((ext_vector_type(8))) short short8;
typedef __attribute__((ext_vector_type(4))) float float4_;

// ---- workspace (uncached exchange; well under R4's proven 1.74 MB) ----
#define WS_BAR 0                 // 17 words @128B stride (2176 B, round 2304)
#define WS_KF  4096              // 2 x 512*64 f32 (double-buffered k) = 262144
#define WS_SGT (4096 + 262144)   // 528*512 f32 = 1081344; total 1347584 B

// ---- module-persistent bf16 fragment-major weights (written every launch) ----
__device__ unsigned short g_w3f[64 * 33 * 4 * 64 * 8];  // 8.65 MB
__device__ unsigned short g_w0f[8 * 2 * 64 * 8];
__device__ unsigned short g_w1f[8 * 4 * 64 * 8];
__device__ unsigned short g_w2f[8 * 4 * 64 * 8];

#define LOADC(p)    __hip_atomic_load((p),  __ATOMIC_RELAXED, __HIP_MEMORY_SCOPE_SYSTEM)
#define STOREC(p,v) __hip_atomic_store((p), (v), __ATOMIC_RELAXED, __HIP_MEMORY_SCOPE_SYSTEM)

__device__ __forceinline__ unsigned short f2bf(float x) {
  union { float f; unsigned u; } v; v.f = x;
  return (unsigned short)((v.u + 0x7fffu + ((v.u >> 16) & 1u)) >> 16);
}
__device__ __forceinline__ float fast_exp(float x) {
  return __builtin_amdgcn_exp2f(x * 1.4426950408889634f);
}
__device__ __forceinline__ float fast_tanh(float x) {
  float e = __builtin_amdgcn_exp2f(x * 2.8853900817779268f);
  return fmaf(-2.0f, __builtin_amdgcn_rcpf(e + 1.0f), 1.0f);
}
__device__ __forceinline__ float fast_silu(float x) {
  float e = fast_exp(-x);
  return x * __builtin_amdgcn_rcpf(1.0f + e);
}
__device__ __forceinline__ void store8bf(unsigned short* dst, const float* src) {
  union { unsigned long long u[2]; unsigned short s[8]; } p;
  #pragma unroll
  for (int j = 0; j < 8; ++j) p.s[j] = f2bf(src[j]);
  STOREC((unsigned long long*)dst, p.u[0]);
  STOREC((unsigned long long*)dst + 1, p.u[1]);
}

// Hierarchical arrival (8 leaves x 32) + replicated-gen release (8 gen words).
// Monotone counters -> no reset/ABA. __syncthreads() drains vmcnt before arrival.
__device__ __forceinline__ void gridbar(unsigned* bar, int g, unsigned bn) {
  __syncthreads();
  if (threadIdx.x == 0) {
    unsigned* leaf = bar + 32 * (g & 7);
    unsigned* root = bar + 32 * 8;
    unsigned* gen  = bar + 32 * (9 + (g & 7));
    unsigned a = __hip_atomic_fetch_add(leaf, 1u, __ATOMIC_RELAXED, __HIP_MEMORY_SCOPE_SYSTEM);
    if (a == 32u * bn - 1u) {
      unsigned r = __hip_atomic_fetch_add(root, 1u, __ATOMIC_RELAXED, __HIP_MEMORY_SCOPE_SYSTEM);
      if (r == 8u * bn - 1u) {
        #pragma unroll
        for (int j = 0; j < 8; ++j) STOREC(bar + 32 * (9 + j), bn);
      }
    }
    while (LOADC(gen) < bn) __builtin_amdgcn_s_sleep(1);
  }
  __syncthreads();
}

template<int SIN>
__device__ __forceinline__ void rk_stage(
    bool first, int stepi, int sg, int g, int h, int R,
    float (&kh)[6][16], float (&y)[16], float t0v, float dtv,
    unsigned char* ws, unsigned* BAR, unsigned& bseq, int& last_idx,
    const float* logsig, const float* b0, const float* b1, const float* b2,
    unsigned short* SAy, unsigned short* S1, unsigned short* S2,
    float* kred, float* b3lds, float* intv, int* sidxp) {
  const int tid = threadIdx.x;
  const int lane = tid & 63, wv = tid >> 6;
  const int col = lane & 15, qd = lane >> 4;
  float* KF0 = (float*)(ws + WS_KF);
  float* SGT = (float*)(ws + WS_SGT);
  float* kbuf = (float*)S2;  // S2 free at stage start

  // ---- ingest k of previous stage (coalesced 32 KB coop load) ----
  if (!first) {
    const float* src = KF0 + ((sg & 1) ^ 1) * 32768 + R * 64;
    #pragma unroll
    for (int it = 0; it < 4; ++it) {
      const int o = it * 2048 + tid * 4;
      unsigned long long u0 = LOADC((const unsigned long long*)(src + o));
      unsigned long long u1 = LOADC((const unsigned long long*)(src + o) + 1);
      *(unsigned long long*)(kbuf + o) = u0;
      *((unsigned long long*)(kbuf + o) + 1) = u1;
    }
    __syncthreads();
    constexpr int pi = (SIN == 0) ? 5 : SIN - 1;
    #pragma unroll
    for (int i = 0; i < 16; ++i)
      kh[pi][i] = kbuf[(wv * 16 + i) * 64 + lane];
  }

  // ---- RK combine -> yst ----
  float yst[16];
  if constexpr (SIN == 0) {
    if (!first) {
      #pragma unroll
      for (int i = 0; i < 16; ++i)
        y[i] += dtv * (0.09646076681806523f * kh[0][i] + 0.01f * kh[1][i]
                     + 0.4798896504144996f * kh[2][i] + 1.379008574103742f * kh[3][i]
                     - 3.290069515436081f * kh[4][i] + 2.324710524099774f * kh[5][i]);
    }
    #pragma unroll
    for (int i = 0; i < 16; ++i) yst[i] = y[i];
  } else if constexpr (SIN == 1) {
    #pragma unroll
    for (int i = 0; i < 16; ++i) yst[i] = y[i] + dtv * (0.161f * kh[0][i]);
  } else if constexpr (SIN == 2) {
    #pragma unroll
    for (int i = 0; i < 16; ++i)
      yst[i] = y[i] + dtv * (-0.008480655492356989f * kh[0][i] + 0.335480655492357f * kh[1][i]);
  } else if constexpr (SIN == 3) {
    #pragma unroll
    for (int i = 0; i < 16; ++i)
      yst[i] = y[i] + dtv * (2.8971530571054935f * kh[0][i] - 6.359448489975075f * kh[1][i]
                           + 4.3622954328695815f * kh[2][i]);
  } else if constexpr (SIN == 4) {
    #pragma unroll
    for (int i = 0; i < 16; ++i)
      yst[i] = y[i] + dtv * (5.325864828439257f * kh[0][i] - 11.748883564062828f * kh[1][i]
                           + 7.4955393428898365f * kh[2][i] - 0.09249506636175525f * kh[3][i]);
  } else {
    #pragma unroll
    for (int i = 0; i < 16; ++i)
      yst[i] = y[i] + dtv * (5.86145544294642f * kh[0][i] - 12.92096931784711f * kh[1][i]
                           + 8.159367898576159f * kh[2][i] - 0.071584973281401f * kh[3][i]
                           - 0.028269050394068383f * kh[4][i]);
  }

  // ---- stage time + searchsorted (identical in every block) ----
  {
    float t_s = __fadd_rn(t0v, __fmul_rn((float)stepi, dtv));
    if constexpr (SIN != 0) {
      constexpr float c = (SIN == 1) ? 0.161f : (SIN == 2) ? 0.327f : (SIN == 3) ? 0.9f
                        : (SIN == 4) ? 0.9800255409045097f : 1.0f;
      t_s = __fadd_rn(t_s, __fmul_rn(c, dtv));
    }
    if (tid < 64) {
      unsigned long long m = __ballot(intv[tid] < t_s);
      if (tid == 0) *sidxp = (int)__popcll(m);
    }
  }

  // ---- y -> bf16 A-frag staging (k=64) ----
  {
    const int kb0 = lane >> 5, qd0 = (lane >> 3) & 3, j0 = lane & 7;
    unsigned short* dst = SAy + (wv * 2 + kb0) * 512 + qd0 * 128 + j0;
    #pragma unroll
    for (int i = 0; i < 16; ++i) dst[i * 8] = f2bf(yst[i]);
  }
  __syncthreads();

  const int idx = *sidxp;
  const bool rebuild = (idx != last_idx);
  if (rebuild) {
    last_idx = idx;
    if (g < 33) {  // blocks 0..32 scatter one 16-wide l stripe (rare)
      const int l0t = g * 16;
      const int part = tid & 3;
      #pragma unroll 1
      for (int bi = 0; bi < 4; ++bi) {
        const int b = bi * 128 + (tid >> 2);
        const float* srow = logsig + ((size_t)b * 65 + idx) * 529 + 1 + l0t + part * 4;
        #pragma unroll
        for (int c2 = 0; c2 < 4; ++c2)
          STOREC(&SGT[(size_t)(l0t + part * 4 + c2) * 512 + b], srow[c2]);
      }
    }
  }

  // ---- MLP layer 0: y(64) -> h1(128), MFMA, wave wv owns n-tile wv ----
  {
    const float bv = b0[wv * 16 + col];
    float4_ acc[8];
    #pragma unroll
    for (int m = 0; m < 8; ++m) { acc[m][0] = bv; acc[m][1] = bv; acc[m][2] = bv; acc[m][3] = bv; }
    #pragma unroll
    for (int kb = 0; kb < 2; ++kb) {
      const short8 bf = *(const short8*)(g_w0f + ((wv * 2 + kb) * 64 + lane) * 8);
      #pragma unroll
      for (int m = 0; m < 8; ++m) {
        const short8 af = *(const short8*)(SAy + (m * 2 + kb) * 512 + lane * 8);
        acc[m] = __builtin_amdgcn_mfma_f32_16x16x32_bf16(af, bf, acc[m], 0, 0, 0);
      }
    }
    const int n = wv * 16 + col, kbp = n >> 5, qdp = (n >> 3) & 3, jp = n & 7;
    unsigned short* dst = S1 + qdp * 128 + jp;
    #pragma unroll
    for (int m = 0; m < 8; ++m)
      #pragma unroll
      for (int r = 0; r < 4; ++r)
        dst[(m * 4 + kbp) * 512 + (qd * 4 + r) * 8] = f2bf(fast_silu(acc[m][r]));
  }
  __syncthreads();
  // ---- MLP layer 1: h1 -> h2 ----
  {
    const float bv = b1[wv * 16 + col];
    float4_ acc[8];
    #pragma unroll
    for (int m = 0; m < 8; ++m) { acc[m][0] = bv; acc[m][1] = bv; acc[m][2] = bv; acc[m][3] = bv; }
    #pragma unroll
    for (int kb = 0; kb < 4; ++kb) {
      const short8 bf = *(const short8*)(g_w1f + ((wv * 4 + kb) * 64 + lane) * 8);
      #pragma unroll
      for (int m = 0; m < 8; ++m) {
        const short8 af = *(const short8*)(S1 + (m * 4 + kb) * 512 + lane * 8);
        acc[m] = __builtin_amdgcn_mfma_f32_16x16x32_bf16(af, bf, acc[m], 0, 0, 0);
      }
    }
    const int n = wv * 16 + col, kbp = n >> 5, qdp = (n >> 3) & 3, jp = n & 7;
    unsigned short* dst = S2 + qdp * 128 + jp;
    #pragma unroll
    for (int m = 0; m < 8; ++m)
      #pragma unroll
      for (int r = 0; r < 4; ++r)
        dst[(m * 4 + kbp) * 512 + (qd * 4 + r) * 8] = f2bf(fast_silu(acc[m][r]));
  }
  __syncthreads();
  // ---- MLP layer 2: h2 -> hdn (into S1, A-frag layout for main GEMM) ----
  {
    const float bv = b2[wv * 16 + col];
    float4_ acc[8];
    #pragma unroll
    for (int m = 0; m < 8; ++m) { acc[m][0] = bv; acc[m][1] = bv; acc[m][2] = bv; acc[m][3] = bv; }
    #pragma unroll
    for (int kb = 0; kb < 4; ++kb) {
      const short8 bf = *(const short8*)(g_w2f + ((wv * 4 + kb) * 64 + lane) * 8);
      #pragma unroll
      for (int m = 0; m < 8; ++m) {
        const short8 af = *(const short8*)(S2 + (m * 4 + kb) * 512 + lane * 8);
        acc[m] = __builtin_amdgcn_mfma_f32_16x16x32_bf16(af, bf, acc[m], 0, 0, 0);
      }
    }
    const int n = wv * 16 + col, kbp = n >> 5, qdp = (n >> 3) & 3, jp = n & 7;
    unsigned short* dst = S1 + qdp * 128 + jp;
    #pragma unroll
    for (int m = 0; m < 8; ++m)
      #pragma unroll
      for (int r = 0; r < 4; ++r)
        dst[(m * 4 + kbp) * 512 + (qd * 4 + r) * 8] = f2bf(fast_silu(acc[m][r]));
  }
  __syncthreads();

  if (rebuild) {  // SGT producers must be globally visible before GEMM reads
    ++bseq; gridbar(BAR, g, bseq);
    __builtin_amdgcn_fence(__ATOMIC_ACQUIRE, "agent");  // drop stale cached SGT
  }

  // ---- main GEMM (128 x 528 x 128) + tanh + sig contraction ----
  {
    float kp[8][4];
    #pragma unroll
    for (int m = 0; m < 8; ++m)
      #pragma unroll
      for (int r = 0; r < 4; ++r) kp[m][r] = 0.0f;
    const int ntn = (wv == 7) ? 5 : 4;
    for (int ni = 0; ni < ntn; ++ni) {
      const int nt = wv * 4 + ni;
      const int l = nt * 16 + col;
      const float bv = b3lds[l];
      float4_ acc[8];
      #pragma unroll
      for (int m = 0; m < 8; ++m) { acc[m][0] = bv; acc[m][1] = bv; acc[m][2] = bv; acc[m][3] = bv; }
      #pragma unroll
      for (int kb = 0; kb < 4; ++kb) {
        const short8 bf = *(const short8*)(g_w3f + (size_t)(((h * 33 + nt) * 4 + kb) * 64 + lane) * 8);
        #pragma unroll
        for (int m = 0; m < 8; ++m) {
          const short8 af = *(const short8*)(S1 + (m * 4 + kb) * 512 + lane * 8);
          acc[m] = __builtin_amdgcn_mfma_f32_16x16x32_bf16(af, bf, acc[m], 0, 0, 0);
        }
      }
      #pragma unroll
      for (int m = 0; m < 8; ++m) {
        const float4_ s4 = *(const float4_*)(SGT + (size_t)l * 512 + R + m * 16 + qd * 4);
        #pragma unroll
        for (int r = 0; r < 4; ++r)
          kp[m][r] = fmaf(fast_tanh(acc[m][r]), s4[r], kp[m][r]);
      }
    }
    #pragma unroll
    for (int m = 0; m < 8; ++m)
      #pragma unroll
      for (int r = 0; r < 4; ++r) {
        float v = kp[m][r];
        v += __shfl_xor(v, 1); v += __shfl_xor(v, 2);
        v += __shfl_xor(v, 4); v += __shfl_xor(v, 8);
        kp[m][r] = v;
      }
    if (col == 0) {
      #pragma unroll
      for (int m = 0; m < 8; ++m)
        #pragma unroll
        for (int r = 0; r < 4; ++r)
          kred[wv * 128 + m * 16 + qd * 4 + r] = kp[m][r];
    }
  }
  __syncthreads();
  if (tid < 128) {
    float s = 0.0f;
    #pragma unroll
    for (int w = 0; w < 8; ++w) s += kred[w * 128 + tid];
    float* KFw = KF0 + (sg & 1) * 32768;
    STOREC(&KFw[(size_t)(R + tid) * 64 + h], s);
  }
  ++bseq; gridbar(BAR, g, bseq);
}

__global__ void __launch_bounds__(NTHR, 2)
rde_kernel(const float* __restrict__ ts, const float* __restrict__ logsig,
           const float* __restrict__ x0, const float* __restrict__ intervals,
           const float* __restrict__ w0, const float* __restrict__ b0,
           const float* __restrict__ w1, const float* __restrict__ b1,
           const float* __restrict__ w2, const float* __restrict__ b2,
           const float* __restrict__ w3, const float* __restrict__ b3,
           const float* __restrict__ l1w, const float* __restrict__ l1b,
           const float* __restrict__ l2w, const float* __restrict__ l2b,
           float* out, unsigned char* ws) {
  const int tid = threadIdx.x;
  const int g = blockIdx.x;
  const int h = g & 63;        // owned head
  const int R = (g >> 6) * 128; // owned batch-row base
  const int lane = tid & 63, wv = tid >> 6;

  unsigned* BAR = (unsigned*)(ws + WS_BAR);
  unsigned bseq = 0;
  int last_idx = -1;

  __shared__ __attribute__((aligned(16))) unsigned short SAy[8192];
  __shared__ __attribute__((aligned(16))) unsigned short S1[16384];
  __shared__ __attribute__((aligned(16))) unsigned short S2[16384];
  __shared__ float kred[1024];
  __shared__ float b3lds[528];
  __shared__ float intv[64];
  __shared__ int sidx;

  if (tid < 64) intv[tid] = intervals[tid];
  for (int e = tid; e < 528; e += NTHR) b3lds[e] = b3[(size_t)h * 528 + e];

  // ---- weight conversion to fragment-major bf16 (distributed over grid) ----
  for (int e = g * NTHR + tid; e < 540672; e += NBLK * NTHR) {  // w3: 64*33*4*64
    const int ln = e & 63, kb = (e >> 6) & 3, r = e >> 8;
    const int nt = r % 33, hh2 = r / 33;
    store8bf(g_w3f + (size_t)e * 8,
             w3 + ((size_t)(hh2 * 528 + nt * 16 + (ln & 15))) * 128 + kb * 32 + (ln >> 4) * 8);
  }
  for (int e = g * NTHR + tid; e < 1024; e += NBLK * NTHR) {    // w0: 8 nt * 2 kb * 64
    const int ln = e & 63, kb = (e >> 6) & 1, nt = e >> 7;
    store8bf(g_w0f + e * 8, w0 + (size_t)(nt * 16 + (ln & 15)) * 64 + kb * 32 + (ln >> 4) * 8);
  }
  for (int e = g * NTHR + tid; e < 2048; e += NBLK * NTHR) {    // w1: 8 nt * 4 kb * 64
    const int ln = e & 63, kb = (e >> 6) & 3, nt = e >> 8;
    store8bf(g_w1f + e * 8, w1 + (size_t)(nt * 16 + (ln & 15)) * 128 + kb * 32 + (ln >> 4) * 8);
  }
  for (int e = g * NTHR + tid; e < 2048; e += NBLK * NTHR) {    // w2: 8 nt * 4 kb * 64
    const int ln = e & 63, kb = (e >> 6) & 3, nt = e >> 8;
    store8bf(g_w2f + e * 8, w2 + (size_t)(nt * 16 + (ln & 15)) * 128 + kb * 32 + (ln >> 4) * 8);
  }

  // ---- y0 = x0 @ l1w.T + l1b for own 128 rows (thread: rows wv*16+i, head lane) ----
  float y[16], kh[6][16];
  #pragma unroll
  for (int i = 0; i < 16; ++i) {
    const int b = R + wv * 16 + i;
    float acc = l1b[lane];
    const float* xr = x0 + (size_t)b * 32;
    const float* wr = l1w + (size_t)lane * 32;
    #pragma unroll
    for (int d = 0; d < 32; ++d) acc = fmaf(xr[d], wr[d], acc);
    y[i] = acc;
  }
  const float t0v = ts[0];
  const float dtv = (ts[128] - t0v) * (1.0f / 256.0f);

  ++bseq; gridbar(BAR, g, bseq);
  __builtin_amdgcn_fence(__ATOMIC_ACQUIRE, "agent");  // see fresh g_w*f everywhere

  // ---- 256 steps x 6 stages ----
  for (int stepi = 0; stepi < 256; ++stepi) {
    const int sg = stepi * 6;
    rk_stage<0>(stepi == 0, stepi, sg + 0, g, h, R, kh, y, t0v, dtv, ws, BAR, bseq,
                last_idx, logsig, b0, b1, b2, SAy, S1, S2, kred, b3lds, intv, &sidx);
    rk_stage<1>(false, stepi, sg + 1, g, h, R, kh, y, t0v, dtv, ws, BAR, bseq,
                last_idx, logsig, b0, b1, b2, SAy, S1, S2, kred, b3lds, intv, &sidx);
    rk_stage<2>(false, stepi, sg + 2, g, h, R, kh, y, t0v, dtv, ws, BAR, bseq,
                last_idx, logsig, b0, b1, b2, SAy, S1, S2, kred, b3lds, intv, &sidx);
    rk_stage<3>(false, stepi, sg + 3, g, h, R, kh, y, t0v, dtv, ws, BAR, bseq,
                last_idx, logsig, b0, b1, b2, SAy, S1, S2, kred, b3lds, intv, &sidx);
    rk_stage<4>(false, stepi, sg + 4, g, h, R, kh, y, t0v, dtv, ws, BAR, bseq,
                last_idx, logsig, b0, b1, b2, SAy, S1, S2, kred, b3lds, intv, &sidx);
    rk_stage<5>(false, stepi, sg + 5, g, h, R, kh, y, t0v, dtv, ws, BAR, bseq,
                last_idx, logsig, b0, b1, b2, SAy, S1, S2, kred, b3lds, intv, &sidx);
  }

  // ---- epilogue: ingest k6 of step 255, final y, head, softmax ----
  {
    float* KF0 = (float*)(ws + WS_KF);
    const float* src = KF0 + 1 * 32768 + R * 64;  // sg=1535 has parity 1
    float* kbuf = (float*)S2;
    #pragma unroll
    for (int it = 0; it < 4; ++it) {
      const int o = it * 2048 + tid * 4;
      unsigned long long u0 = LOADC((const unsigned long long*)(src + o));
      unsigned long long u1 = LOADC((const unsigned long long*)(src + o) + 1);
      *(unsigned long long*)(kbuf + o) = u0;
      *((unsigned long long*)(kbuf + o) + 1) = u1;
    }
    __syncthreads();
    #pragma unroll
    for (int i = 0; i < 16; ++i) kh[5][i] = kbuf[(wv * 16 + i) * 64 + lane];
    #pragma unroll
    for (int i = 0; i < 16; ++i)
      y[i] += dtv * (0.09646076681806523f * kh[0][i] + 0.01f * kh[1][i]
                   + 0.4798896504144996f * kh[2][i] + 1.379008574103742f * kh[3][i]
                   - 3.290069515436081f * kh[4][i] + 2.324710524099774f * kh[5][i]);
    float* yfin = (float*)S1;
    #pragma unroll
    for (int i = 0; i < 16; ++i) yfin[(wv * 16 + i) * 64 + lane] = y[i];
    __syncthreads();
    if (h == 0 && tid < 128) {
      const int b = R + tid;
      float logits[10];
      float mx = -1e30f;
      #pragma unroll
      for (int c = 0; c < 10; ++c) {
        float acc = l2b[c];
        const float* wr = l2w + c * 64;
        #pragma unroll
        for (int k = 0; k < 64; ++k) acc = fmaf(yfin[tid * 64 + k], wr[k], acc);
        logits[c] = acc;
        mx = fmaxf(mx, acc);
      }
      float den = 0.0f, ev[10];
      #pragma unroll
      for (int c = 0; c < 10; ++c) { ev[c] = expf(logits[c] - mx); den += ev[c]; }
      const float rd = 1.0f / den;
      #pragma unroll
      for (int c = 0; c < 10; ++c) out[(size_t)b * 10 + c] = ev[c] * rd;
    }
  }
}

extern "C" void kernel_launch(void* const* d_in, const int* in_sizes, int n_in,
                              void* d_out, int out_size, void* d_ws, size_t ws_size,
                              hipStream_t stream) {
  (void)in_sizes; (void)n_in; (void)out_size; (void)ws_size;
  const float* ts        = (const float*)d_in[0];
  const float* logsig    = (const float*)d_in[1];
  const float* x0        = (const float*)d_in[2];
  const float* intervals = (const float*)d_in[3];
  const float* w0        = (const float*)d_in[4];
  const float* b0        = (const float*)d_in[5];
  const float* w1        = (const float*)d_in[6];
  const float* b1        = (const float*)d_in[7];
  const float* w2        = (const float*)d_in[8];
  const float* b2        = (const float*)d_in[9];
  const float* w3        = (const float*)d_in[10];
  const float* b3        = (const float*)d_in[11];
  const float* l1w       = (const float*)d_in[12];
  const float* l1b       = (const float*)d_in[13];
  const float* l2w       = (const float*)d_in[14];
  const float* l2b       = (const float*)d_in[15];
  float* out = (float*)d_out;
  unsigned char* ws = (unsigned char*)d_ws;

  hipMemsetAsync(d_ws, 0, 2304, stream);  // zero barrier counters

  void* args[] = { &ts, &logsig, &x0, &intervals, &w0, &b0, &w1, &b1,
                   &w2, &b2, &w3, &b3, &l1w, &l1b, &l2w, &l2b, &out, &ws };
  hipLaunchCooperativeKernel((void*)rde_kernel, dim3(NBLK), dim3(NTHR), args, 0, stream);
}

// Round 7
// 39666.388 us; speedup vs baseline: 1.4771x; 1.4771x over previous
//
#include <hip/hip_runtime.h>
#include <stdint.h>

#define NBLK 256
#define NTHR 512

typedef __attribute__((ext_vector_type(8))) short short8;
typedef __attribute__((ext_vector_type(4))) float float4_;

// ---- workspace ----
#define WS_BAR 0                 // 17 words @128B stride (2176 B, round 4096)
#define WS_KF  4096              // 2 x 512*64 f32 (double-buffered k) = 262144
#define WS_SGT (4096 + 262144)   // 528*512 f32 = 1081344; total 1347584 B

// ---- module-persistent bf16 fragment-major MLP weights (small, L2-resident) ----
__device__ unsigned short g_w0f[8 * 2 * 64 * 8];   // 16 KB
__device__ unsigned short g_w1f[8 * 4 * 64 * 8];   // 32 KB
__device__ unsigned short g_w2f[8 * 4 * 64 * 8];   // 32 KB

#define LOADC(p)    __hip_atomic_load((p),  __ATOMIC_RELAXED, __HIP_MEMORY_SCOPE_SYSTEM)
#define STOREC(p,v) __hip_atomic_store((p), (v), __ATOMIC_RELAXED, __HIP_MEMORY_SCOPE_SYSTEM)

__device__ __forceinline__ unsigned short f2bf(float x) {
  union { float f; unsigned u; } v; v.f = x;
  return (unsigned short)((v.u + 0x7fffu + ((v.u >> 16) & 1u)) >> 16);
}
__device__ __forceinline__ float fast_exp(float x) {
  return __builtin_amdgcn_exp2f(x * 1.4426950408889634f);
}
__device__ __forceinline__ float fast_tanh(float x) {
  float e = __builtin_amdgcn_exp2f(x * 2.8853900817779268f);
  return fmaf(-2.0f, __builtin_amdgcn_rcpf(e + 1.0f), 1.0f);
}
__device__ __forceinline__ float fast_silu(float x) {
  float e = fast_exp(-x);
  return x * __builtin_amdgcn_rcpf(1.0f + e);
}
__device__ __forceinline__ void store8bf(unsigned short* dst, const float* src) {
  union { unsigned long long u[2]; unsigned short s[8]; } p;
  #pragma unroll
  for (int j = 0; j < 8; ++j) p.s[j] = f2bf(src[j]);
  STOREC((unsigned long long*)dst, p.u[0]);
  STOREC((unsigned long long*)dst + 1, p.u[1]);
}

// Hierarchical arrival (8 leaves x 32) + replicated-gen release. Monotone counters.
__device__ __forceinline__ void gridbar(unsigned* bar, int g, unsigned bn) {
  __syncthreads();
  if (threadIdx.x == 0) {
    unsigned* leaf = bar + 32 * (g & 7);
    unsigned* root = bar + 32 * 8;
    unsigned* gen  = bar + 32 * (9 + (g & 7));
    unsigned a = __hip_atomic_fetch_add(leaf, 1u, __ATOMIC_RELAXED, __HIP_MEMORY_SCOPE_SYSTEM);
    if (a == 32u * bn - 1u) {
      unsigned r = __hip_atomic_fetch_add(root, 1u, __ATOMIC_RELAXED, __HIP_MEMORY_SCOPE_SYSTEM);
      if (r == 8u * bn - 1u) {
        #pragma unroll
        for (int j = 0; j < 8; ++j) STOREC(bar + 32 * (9 + j), bn);
      }
    }
    while (LOADC(gen) < bn) __builtin_amdgcn_s_sleep(1);
  }
  __syncthreads();
}

template<int SIN>
__device__ __forceinline__ void rk_stage(
    bool first, int stepi, int sg, int g, int h, int R,
    float (&kh)[6][16], float (&y)[16], float t0v, float dtv,
    unsigned char* ws, unsigned* BAR, unsigned& bseq, int& last_idx,
    const float* logsig, float b0v, float b1v, float b2v,
    unsigned short* w3lds, unsigned short* bufA, unsigned short* bufB,
    float* kred, float* b3lds, float* intv, int* sidxp) {
  const int tid = threadIdx.x;
  const int lane = tid & 63, wv = tid >> 6;
  const int col = lane & 15, qd = lane >> 4;
  float* KF0 = (float*)(ws + WS_KF);
  float* SGT = (float*)(ws + WS_SGT);

  // ---- ingest k of previous stage: 16 coalesced uncached dword loads/thread ----
  if (!first) {
    const float* KFr = KF0 + ((sg & 1) ^ 1) * 32768;
    constexpr int pi = (SIN == 0) ? 5 : SIN - 1;
    #pragma unroll
    for (int i = 0; i < 16; ++i)
      kh[pi][i] = LOADC(&KFr[(size_t)(R + wv * 16 + i) * 64 + lane]);
  }

  // ---- RK combine -> yst (registers) ----
  float yst[16];
  if constexpr (SIN == 0) {
    if (!first) {
      #pragma unroll
      for (int i = 0; i < 16; ++i)
        y[i] += dtv * (0.09646076681806523f * kh[0][i] + 0.01f * kh[1][i]
                     + 0.4798896504144996f * kh[2][i] + 1.379008574103742f * kh[3][i]
                     - 3.290069515436081f * kh[4][i] + 2.324710524099774f * kh[5][i]);
    }
    #pragma unroll
    for (int i = 0; i < 16; ++i) yst[i] = y[i];
  } else if constexpr (SIN == 1) {
    #pragma unroll
    for (int i = 0; i < 16; ++i) yst[i] = y[i] + dtv * (0.161f * kh[0][i]);
  } else if constexpr (SIN == 2) {
    #pragma unroll
    for (int i = 0; i < 16; ++i)
      yst[i] = y[i] + dtv * (-0.008480655492356989f * kh[0][i] + 0.335480655492357f * kh[1][i]);
  } else if constexpr (SIN == 3) {
    #pragma unroll
    for (int i = 0; i < 16; ++i)
      yst[i] = y[i] + dtv * (2.8971530571054935f * kh[0][i] - 6.359448489975075f * kh[1][i]
                           + 4.3622954328695815f * kh[2][i]);
  } else if constexpr (SIN == 4) {
    #pragma unroll
    for (int i = 0; i < 16; ++i)
      yst[i] = y[i] + dtv * (5.325864828439257f * kh[0][i] - 11.748883564062828f * kh[1][i]
                           + 7.4955393428898365f * kh[2][i] - 0.09249506636175525f * kh[3][i]);
  } else {
    #pragma unroll
    for (int i = 0; i < 16; ++i)
      yst[i] = y[i] + dtv * (5.86145544294642f * kh[0][i] - 12.92096931784711f * kh[1][i]
                           + 8.159367898576159f * kh[2][i] - 0.071584973281401f * kh[3][i]
                           - 0.028269050394068383f * kh[4][i]);
  }

  // ---- stage time + searchsorted (identical in every block) ----
  {
    float t_s = __fadd_rn(t0v, __fmul_rn((float)stepi, dtv));
    if constexpr (SIN != 0) {
      constexpr float c = (SIN == 1) ? 0.161f : (SIN == 2) ? 0.327f : (SIN == 3) ? 0.9f
                        : (SIN == 4) ? 0.9800255409045097f : 1.0f;
      t_s = __fadd_rn(t_s, __fmul_rn(c, dtv));
    }
    if (tid < 64) {
      unsigned long long m = __ballot(intv[tid] < t_s);
      if (tid == 0) *sidxp = (int)__popcll(m);
    }
  }
  __syncthreads();

  const int idx = *sidxp;
  const bool rebuild = (idx != last_idx);
  if (rebuild) {
    last_idx = idx;
    if (g < 33) {  // blocks 0..32 scatter one 16-wide l stripe (rare, ~65 times)
      const int l0t = g * 16;
      const int part = tid & 3;
      #pragma unroll 1
      for (int bi = 0; bi < 4; ++bi) {
        const int b = bi * 128 + (tid >> 2);
        const float* srow = logsig + ((size_t)b * 65 + idx) * 529 + 1 + l0t + part * 4;
        #pragma unroll
        for (int c2 = 0; c2 < 4; ++c2)
          STOREC(&SGT[(size_t)(l0t + part * 4 + c2) * 512 + b], srow[c2]);
      }
    }
    ++bseq; gridbar(BAR, g, bseq);
    __builtin_amdgcn_fence(__ATOMIC_ACQUIRE, "agent");  // drop stale cached SGT (rare)
  }

  // ---- 4 passes of 32 rows: MLP (3 MFMA layers) + GEMM, all operands LDS-local ----
  #pragma unroll 1
  for (int gi = 0; gi < 4; ++gi) {
    // stage y rows 32*gi..+31 into bufA (A-frag layout, K=64) by waves 2gi, 2gi+1
    if ((wv >> 1) == gi) {
      const int mp = wv & 1;
      const int kb0 = lane >> 5, qd0 = (lane >> 3) & 3, j0 = lane & 7;
      unsigned short* dst = bufA + (mp * 2 + kb0) * 512 + qd0 * 128 + j0;
      #pragma unroll
      for (int i = 0; i < 16; ++i) dst[i * 8] = f2bf(yst[i]);
    }
    __syncthreads();
    // L0: y(64) -> h1(128), bufA -> bufB
    {
      float4_ acc[2];
      #pragma unroll
      for (int m = 0; m < 2; ++m) { acc[m][0]=b0v; acc[m][1]=b0v; acc[m][2]=b0v; acc[m][3]=b0v; }
      #pragma unroll
      for (int kb = 0; kb < 2; ++kb) {
        const short8 bf = *(const short8*)(g_w0f + ((wv * 2 + kb) * 64 + lane) * 8);
        #pragma unroll
        for (int m = 0; m < 2; ++m) {
          const short8 af = *(const short8*)(bufA + (m * 2 + kb) * 512 + lane * 8);
          acc[m] = __builtin_amdgcn_mfma_f32_16x16x32_bf16(af, bf, acc[m], 0, 0, 0);
        }
      }
      const int n = wv * 16 + col, kbp = n >> 5, qdp = (n >> 3) & 3, jp = n & 7;
      unsigned short* dst = bufB + qdp * 128 + jp;
      #pragma unroll
      for (int m = 0; m < 2; ++m)
        #pragma unroll
        for (int r = 0; r < 4; ++r)
          dst[(m * 4 + kbp) * 512 + (qd * 4 + r) * 8] = f2bf(fast_silu(acc[m][r]));
    }
    __syncthreads();
    // L1: h1 -> h2, bufB -> bufA
    {
      float4_ acc[2];
      #pragma unroll
      for (int m = 0; m < 2; ++m) { acc[m][0]=b1v; acc[m][1]=b1v; acc[m][2]=b1v; acc[m][3]=b1v; }
      #pragma unroll
      for (int kb = 0; kb < 4; ++kb) {
        const short8 bf = *(const short8*)(g_w1f + ((wv * 4 + kb) * 64 + lane) * 8);
        #pragma unroll
        for (int m = 0; m < 2; ++m) {
          const short8 af = *(const short8*)(bufB + (m * 4 + kb) * 512 + lane * 8);
          acc[m] = __builtin_amdgcn_mfma_f32_16x16x32_bf16(af, bf, acc[m], 0, 0, 0);
        }
      }
      const int n = wv * 16 + col, kbp = n >> 5, qdp = (n >> 3) & 3, jp = n & 7;
      unsigned short* dst = bufA + qdp * 128 + jp;
      #pragma unroll
      for (int m = 0; m < 2; ++m)
        #pragma unroll
        for (int r = 0; r < 4; ++r)
          dst[(m * 4 + kbp) * 512 + (qd * 4 + r) * 8] = f2bf(fast_silu(acc[m][r]));
    }
    __syncthreads();
    // L2: h2 -> hdn, bufA -> bufB
    {
      float4_ acc[2];
      #pragma unroll
      for (int m = 0; m < 2; ++m) { acc[m][0]=b2v; acc[m][1]=b2v; acc[m][2]=b2v; acc[m][3]=b2v; }
      #pragma unroll
      for (int kb = 0; kb < 4; ++kb) {
        const short8 bf = *(const short8*)(g_w2f + ((wv * 4 + kb) * 64 + lane) * 8);
        #pragma unroll
        for (int m = 0; m < 2; ++m) {
          const short8 af = *(const short8*)(bufA + (m * 4 + kb) * 512 + lane * 8);
          acc[m] = __builtin_amdgcn_mfma_f32_16x16x32_bf16(af, bf, acc[m], 0, 0, 0);
        }
      }
      const int n = wv * 16 + col, kbp = n >> 5, qdp = (n >> 3) & 3, jp = n & 7;
      unsigned short* dst = bufB + qdp * 128 + jp;
      #pragma unroll
      for (int m = 0; m < 2; ++m)
        #pragma unroll
        for (int r = 0; r < 4; ++r)
          dst[(m * 4 + kbp) * 512 + (qd * 4 + r) * 8] = f2bf(fast_silu(acc[m][r]));
    }
    __syncthreads();
    // GEMM 32 x 528 x 128: A=hdn(bufB), B=w3lds, + tanh + sig contraction
    {
      short8 af2[2][4];
      #pragma unroll
      for (int m = 0; m < 2; ++m)
        #pragma unroll
        for (int kb = 0; kb < 4; ++kb)
          af2[m][kb] = *(const short8*)(bufB + (m * 4 + kb) * 512 + lane * 8);
      float kp[2][4];
      #pragma unroll
      for (int m = 0; m < 2; ++m)
        #pragma unroll
        for (int r = 0; r < 4; ++r) kp[m][r] = 0.0f;
      const int ntn = (wv == 0) ? 5 : 4;
      #pragma unroll 1
      for (int ni = 0; ni < ntn; ++ni) {
        const int nt = wv + 8 * ni;        // 8 waves cover nt 0..32
        const int l = nt * 16 + col;
        const float bv = b3lds[l];
        float4_ acc2[2];
        #pragma unroll
        for (int m = 0; m < 2; ++m) { acc2[m][0]=bv; acc2[m][1]=bv; acc2[m][2]=bv; acc2[m][3]=bv; }
        #pragma unroll
        for (int kb = 0; kb < 4; ++kb) {
          const short8 bf = *(const short8*)(w3lds + ((nt * 4 + kb) * 64 + lane) * 8);
          acc2[0] = __builtin_amdgcn_mfma_f32_16x16x32_bf16(af2[0][kb], bf, acc2[0], 0, 0, 0);
          acc2[1] = __builtin_amdgcn_mfma_f32_16x16x32_bf16(af2[1][kb], bf, acc2[1], 0, 0, 0);
        }
        #pragma unroll
        for (int m = 0; m < 2; ++m) {
          const float4_ s4 = *(const float4_*)(SGT + (size_t)l * 512 + R + 32 * gi + 16 * m + qd * 4);
          #pragma unroll
          for (int r = 0; r < 4; ++r)
            kp[m][r] = fmaf(fast_tanh(acc2[m][r]), s4[r], kp[m][r]);
        }
      }
      #pragma unroll
      for (int m = 0; m < 2; ++m)
        #pragma unroll
        for (int r = 0; r < 4; ++r) {
          float v = kp[m][r];
          v += __shfl_xor(v, 1); v += __shfl_xor(v, 2);
          v += __shfl_xor(v, 4); v += __shfl_xor(v, 8);
          kp[m][r] = v;
        }
      if (col == 0) {
        #pragma unroll
        for (int m = 0; m < 2; ++m)
          #pragma unroll
          for (int r = 0; r < 4; ++r)
            kred[wv * 128 + 32 * gi + 16 * m + qd * 4 + r] = kp[m][r];
      }
    }
  }
  __syncthreads();
  if (tid < 128) {
    float s = 0.0f;
    #pragma unroll
    for (int w = 0; w < 8; ++w) s += kred[w * 128 + tid];
    float* KFw = KF0 + (sg & 1) * 32768;
    STOREC(&KFw[(size_t)(R + tid) * 64 + h], s);
  }
  ++bseq; gridbar(BAR, g, bseq);
}

__global__ void __launch_bounds__(NTHR, 2)
rde_kernel(const float* __restrict__ ts, const float* __restrict__ logsig,
           const float* __restrict__ x0, const float* __restrict__ intervals,
           const float* __restrict__ w0, const float* __restrict__ b0,
           const float* __restrict__ w1, const float* __restrict__ b1,
           const float* __restrict__ w2, const float* __restrict__ b2,
           const float* __restrict__ w3, const float* __restrict__ b3,
           const float* __restrict__ l1w, const float* __restrict__ l1b,
           const float* __restrict__ l2w, const float* __restrict__ l2b,
           float* out, unsigned char* ws) {
  const int tid = threadIdx.x;
  const int g = blockIdx.x;
  const int h = g & 63;          // owned head
  const int R = (g >> 6) * 128;  // owned batch-row base
  const int lane = tid & 63, wv = tid >> 6;
  const int col = lane & 15;

  unsigned* BAR = (unsigned*)(ws + WS_BAR);
  unsigned bseq = 0;
  int last_idx = -1;

  __shared__ __attribute__((aligned(16))) unsigned short w3lds[67584]; // 135.2 KB
  __shared__ __attribute__((aligned(16))) unsigned short bufA[4096];   // 8 KB
  __shared__ __attribute__((aligned(16))) unsigned short bufB[4096];   // 8 KB
  __shared__ float kred[1024];
  __shared__ float b3lds[528];
  __shared__ float intv[64];
  __shared__ int sidx;

  if (tid < 64) intv[tid] = intervals[tid];
  for (int e = tid; e < 528; e += NTHR) b3lds[e] = b3[(size_t)h * 528 + e];

  // ---- w3 head-slice -> LDS bf16 fragments (once) ----
  for (int e = tid; e < 8448; e += NTHR) {   // 33 nt * 4 kb * 64 lanes
    const int ln = e & 63, kb = (e >> 6) & 3, nt = e >> 8;
    const float* src = w3 + ((size_t)(h * 528 + nt * 16 + (ln & 15))) * 128 + kb * 32 + (ln >> 4) * 8;
    union { unsigned short s[8]; short8 v; } p;
    #pragma unroll
    for (int j = 0; j < 8; ++j) p.s[j] = f2bf(src[j]);
    *(short8*)(w3lds + e * 8) = p.v;
  }

  // ---- small MLP weights -> fragment-major bf16 globals (blocks 0..3 only) ----
  for (int e = g * NTHR + tid; e < 1024; e += NBLK * NTHR) {    // w0: 8 nt * 2 kb * 64
    const int ln = e & 63, kb = (e >> 6) & 1, nt = e >> 7;
    store8bf(g_w0f + e * 8, w0 + (size_t)(nt * 16 + (ln & 15)) * 64 + kb * 32 + (ln >> 4) * 8);
  }
  for (int e = g * NTHR + tid; e < 2048; e += NBLK * NTHR) {    // w1: 8 nt * 4 kb * 64
    const int ln = e & 63, kb = (e >> 6) & 3, nt = e >> 8;
    store8bf(g_w1f + e * 8, w1 + (size_t)(nt * 16 + (ln & 15)) * 128 + kb * 32 + (ln >> 4) * 8);
  }
  for (int e = g * NTHR + tid; e < 2048; e += NBLK * NTHR) {    // w2: 8 nt * 4 kb * 64
    const int ln = e & 63, kb = (e >> 6) & 3, nt = e >> 8;
    store8bf(g_w2f + e * 8, w2 + (size_t)(nt * 16 + (ln & 15)) * 128 + kb * 32 + (ln >> 4) * 8);
  }

  // ---- y0 = x0 @ l1w.T + l1b for own 128 rows ----
  float y[16], kh[6][16];
  #pragma unroll
  for (int i = 0; i < 16; ++i) {
    const int b = R + wv * 16 + i;
    float acc = l1b[lane];
    const float4_* xr = (const float4_*)(x0 + (size_t)b * 32);
    const float4_* wr = (const float4_*)(l1w + (size_t)lane * 32);
    #pragma unroll
    for (int d = 0; d < 8; ++d) {
      float4_ xv = xr[d], wvv = wr[d];
      acc = fmaf(xv[0], wvv[0], acc); acc = fmaf(xv[1], wvv[1], acc);
      acc = fmaf(xv[2], wvv[2], acc); acc = fmaf(xv[3], wvv[3], acc);
    }
    y[i] = acc;
  }
  const float b0v = b0[wv * 16 + col];
  const float b1v = b1[wv * 16 + col];
  const float b2v = b2[wv * 16 + col];
  const float t0v = ts[0];
  const float dtv = (ts[128] - t0v) * (1.0f / 256.0f);

  ++bseq; gridbar(BAR, g, bseq);
  __builtin_amdgcn_fence(__ATOMIC_ACQUIRE, "agent");  // see fresh g_w*f everywhere

  // ---- 256 steps x 6 stages ----
  for (int stepi = 0; stepi < 256; ++stepi) {
    const int sg = stepi * 6;
    rk_stage<0>(stepi == 0, stepi, sg + 0, g, h, R, kh, y, t0v, dtv, ws, BAR, bseq,
                last_idx, logsig, b0v, b1v, b2v, w3lds, bufA, bufB, kred, b3lds, intv, &sidx);
    rk_stage<1>(false, stepi, sg + 1, g, h, R, kh, y, t0v, dtv, ws, BAR, bseq,
                last_idx, logsig, b0v, b1v, b2v, w3lds, bufA, bufB, kred, b3lds, intv, &sidx);
    rk_stage<2>(false, stepi, sg + 2, g, h, R, kh, y, t0v, dtv, ws, BAR, bseq,
                last_idx, logsig, b0v, b1v, b2v, w3lds, bufA, bufB, kred, b3lds, intv, &sidx);
    rk_stage<3>(false, stepi, sg + 3, g, h, R, kh, y, t0v, dtv, ws, BAR, bseq,
                last_idx, logsig, b0v, b1v, b2v, w3lds, bufA, bufB, kred, b3lds, intv, &sidx);
    rk_stage<4>(false, stepi, sg + 4, g, h, R, kh, y, t0v, dtv, ws, BAR, bseq,
                last_idx, logsig, b0v, b1v, b2v, w3lds, bufA, bufB, kred, b3lds, intv, &sidx);
    rk_stage<5>(false, stepi, sg + 5, g, h, R, kh, y, t0v, dtv, ws, BAR, bseq,
                last_idx, logsig, b0v, b1v, b2v, w3lds, bufA, bufB, kred, b3lds, intv, &sidx);
  }

  // ---- epilogue: ingest k6 of step 255, final y, head, softmax ----
  {
    float* KF0 = (float*)(ws + WS_KF);
    const float* KFr = KF0 + 1 * 32768;  // sg=1535 parity 1
    #pragma unroll
    for (int i = 0; i < 16; ++i)
      kh[5][i] = LOADC(&KFr[(size_t)(R + wv * 16 + i) * 64 + lane]);
    #pragma unroll
    for (int i = 0; i < 16; ++i)
      y[i] += dtv * (0.09646076681806523f * kh[0][i] + 0.01f * kh[1][i]
                   + 0.4798896504144996f * kh[2][i] + 1.379008574103742f * kh[3][i]
                   - 3.290069515436081f * kh[4][i] + 2.324710524099774f * kh[5][i]);
    __syncthreads();                 // w3lds reads all done; reuse as f32 scratch
    float* yfin = (float*)w3lds;
    #pragma unroll
    for (int i = 0; i < 16; ++i) yfin[(wv * 16 + i) * 64 + lane] = y[i];
    __syncthreads();
    if (h == 0 && tid < 128) {
      const int b = R + tid;
      float logits[10];
      float mx = -1e30f;
      #pragma unroll
      for (int c = 0; c < 10; ++c) {
        float acc = l2b[c];
        const float* wr = l2w + c * 64;
        #pragma unroll
        for (int k = 0; k < 64; ++k) acc = fmaf(yfin[tid * 64 + k], wr[k], acc);
        logits[c] = acc;
        mx = fmaxf(mx, acc);
      }
      float den = 0.0f, ev[10];
      #pragma unroll
      for (int c = 0; c < 10; ++c) { ev[c] = expf(logits[c] - mx); den += ev[c]; }
      const float rd = 1.0f / den;
      #pragma unroll
      for (int c = 0; c < 10; ++c) out[(size_t)b * 10 + c] = ev[c] * rd;
    }
  }
}

extern "C" void kernel_launch(void* const* d_in, const int* in_sizes, int n_in,
                              void* d_out, int out_size, void* d_ws, size_t ws_size,
                              hipStream_t stream) {
  (void)in_sizes; (void)n_in; (void)out_size; (void)ws_size;
  const float* ts        = (const float*)d_in[0];
  const float* logsig    = (const float*)d_in[1];
  const float* x0        = (const float*)d_in[2];
  const float* intervals = (const float*)d_in[3];
  const float* w0        = (const float*)d_in[4];
  const float* b0        = (const float*)d_in[5];
  const float* w1        = (const float*)d_in[6];
  const float* b1        = (const float*)d_in[7];
  const float* w2        = (const float*)d_in[8];
  const float* b2        = (const float*)d_in[9];
  const float* w3        = (const float*)d_in[10];
  const float* b3        = (const float*)d_in[11];
  const float* l1w       = (const float*)d_in[12];
  const float* l1b       = (const float*)d_in[13];
  const float* l2w       = (const float*)d_in[14];
  const float* l2b       = (const float*)d_in[15];
  float* out = (float*)d_out;
  unsigned char* ws = (unsigned char*)d_ws;

  hipMemsetAsync(d_ws, 0, 4096, stream);  // zero barrier counters

  void* args[] = { &ts, &logsig, &x0, &intervals, &w0, &b0, &w1, &b1,
                   &w2, &b2, &w3, &b3, &l1w, &l1b, &l2w, &l2b, &out, &ws };
  hipLaunchCooperativeKernel((void*)rde_kernel, dim3(NBLK), dim3(NTHR), args, 0, stream);
}

// Round 8
// 38128.769 us; speedup vs baseline: 1.5366x; 1.0403x over previous
//
#include <hip/hip_runtime.h>
#include <stdint.h>

#define NBLK 256
#define NTHR 512

typedef __attribute__((ext_vector_type(8))) short short8;
typedef __attribute__((ext_vector_type(4))) float float4_;

// ---- workspace ----
// BAR: global barrier set lines 0..16 ; per-Rg sets at lines 32+Rg*16+(0..9)
#define WS_BAR  0                         // memset first 12288 B
#define WS_HDNF 16384                     // hdn fragments: 4Rg * 32 * 512 shorts = 131072 B
#define WS_KF   (16384 + 131072)          // 2 x 512*64 f32 (double-buffered k) = 262144 B
#define WS_SGT  (16384 + 131072 + 262144) // 528*512 f32 = 1081344 B ; total 1490944 B

#define LOADC(p)    __hip_atomic_load((p),  __ATOMIC_RELAXED, __HIP_MEMORY_SCOPE_SYSTEM)
#define STOREC(p,v) __hip_atomic_store((p), (v), __ATOMIC_RELAXED, __HIP_MEMORY_SCOPE_SYSTEM)

__device__ __forceinline__ unsigned short f2bf(float x) {
  union { float f; unsigned u; } v; v.f = x;
  return (unsigned short)((v.u + 0x7fffu + ((v.u >> 16) & 1u)) >> 16);
}
__device__ __forceinline__ float fast_exp(float x) {
  return __builtin_amdgcn_exp2f(x * 1.4426950408889634f);
}
__device__ __forceinline__ float fast_tanh(float x) {
  float e = __builtin_amdgcn_exp2f(x * 2.8853900817779268f);
  return fmaf(-2.0f, __builtin_amdgcn_rcpf(e + 1.0f), 1.0f);
}
__device__ __forceinline__ float fast_silu(float x) {
  float e = fast_exp(-x);
  return x * __builtin_amdgcn_rcpf(1.0f + e);
}

// Global barrier: hierarchical arrival (8 leaves x 32) + replicated-gen release.
__device__ __forceinline__ void gridbar(unsigned* bar, int g, unsigned bn) {
  __syncthreads();
  if (threadIdx.x == 0) {
    unsigned* leaf = bar + 32 * (g & 7);
    unsigned* root = bar + 32 * 8;
    unsigned* gen  = bar + 32 * (9 + (g & 7));
    unsigned a = __hip_atomic_fetch_add(leaf, 1u, __ATOMIC_RELAXED, __HIP_MEMORY_SCOPE_SYSTEM);
    if (a == 32u * bn - 1u) {
      unsigned r = __hip_atomic_fetch_add(root, 1u, __ATOMIC_RELAXED, __HIP_MEMORY_SCOPE_SYSTEM);
      if (r == 8u * bn - 1u) {
        #pragma unroll
        for (int j = 0; j < 8; ++j) STOREC(bar + 32 * (9 + j), bn);
      }
    }
    while (LOADC(gen) < bn) __builtin_amdgcn_s_sleep(1);
  }
  __syncthreads();
}

// Row-group-local barrier over 64 blocks: 8 leaves x 8 (leaf = h&7) + root + gen.
__device__ __forceinline__ void rgbar(unsigned* bar, int h, int Rg, unsigned bn) {
  __syncthreads();
  if (threadIdx.x == 0) {
    unsigned* base = bar + 32 * (32 + Rg * 16);
    unsigned* leaf = base + 32 * (h & 7);
    unsigned* root = base + 32 * 8;
    unsigned* gen  = base + 32 * 9;
    unsigned a = __hip_atomic_fetch_add(leaf, 1u, __ATOMIC_RELAXED, __HIP_MEMORY_SCOPE_SYSTEM);
    if (a == 8u * bn - 1u) {
      unsigned r = __hip_atomic_fetch_add(root, 1u, __ATOMIC_RELAXED, __HIP_MEMORY_SCOPE_SYSTEM);
      if (r == 8u * bn - 1u) STOREC(gen, bn);
    }
    while (LOADC(gen) < bn) __builtin_amdgcn_s_sleep(1);
  }
  __syncthreads();
}

template<int SIN>
__device__ __forceinline__ void rk_stage(
    int stepi, int sg, int g, int h, int Rg, int R,
    float (&kh)[6], float& y, float t0v, float dtv,
    unsigned char* ws, unsigned* BAR, unsigned& gseq, unsigned& rseq, int& last_idx,
    const float* logsig, const float* w0, const float* b0,
    const float* w1, const float* b1, const float* w2, const float* b2,
    unsigned short* w3lds, float* b3lds, float* intv,
    float (*yst)[64], float (*hb1)[128], float (*hb2)[128],
    unsigned short (*hdnS)[128], int* sidxp, int* sidxnp) {
  const int tid = threadIdx.x;
  const int lane = tid & 63, wv = tid >> 6;
  const int col = lane & 15, qd = lane >> 4;
  unsigned* HDNF = (unsigned*)(ws + WS_HDNF);
  float* KF  = (float*)(ws + WS_KF);
  float* SGT = (float*)(ws + WS_SGT);

  // ---- phase 1: ingest k (2 rows), RK combine, tiny MLP ----
  if (sg > 0 && tid < 128) {
    const float* KFr = KF + ((sg & 1) ^ 1) * 32768;
    constexpr int pi = (SIN == 0) ? 5 : SIN - 1;
    kh[pi] = LOADC(&KFr[(size_t)(2 * g + (tid >> 6)) * 64 + (tid & 63)]);
  }
  if (tid < 128) {
    float ystv;
    if constexpr (SIN == 0) {
      if (sg > 0) {
        y += dtv * (0.09646076681806523f * kh[0] + 0.01f * kh[1]
                  + 0.4798896504144996f * kh[2] + 1.379008574103742f * kh[3]
                  - 3.290069515436081f * kh[4] + 2.324710524099774f * kh[5]);
      }
      ystv = y;
    } else if constexpr (SIN == 1) {
      ystv = y + dtv * (0.161f * kh[0]);
    } else if constexpr (SIN == 2) {
      ystv = y + dtv * (-0.008480655492356989f * kh[0] + 0.335480655492357f * kh[1]);
    } else if constexpr (SIN == 3) {
      ystv = y + dtv * (2.8971530571054935f * kh[0] - 6.359448489975075f * kh[1]
                      + 4.3622954328695815f * kh[2]);
    } else if constexpr (SIN == 4) {
      ystv = y + dtv * (5.325864828439257f * kh[0] - 11.748883564062828f * kh[1]
                      + 7.4955393428898365f * kh[2] - 0.09249506636175525f * kh[3]);
    } else {
      ystv = y + dtv * (5.86145544294642f * kh[0] - 12.92096931784711f * kh[1]
                      + 8.159367898576159f * kh[2] - 0.071584973281401f * kh[3]
                      - 0.028269050394068383f * kh[4]);
    }
    yst[tid >> 6][tid & 63] = ystv;
  }
  // stage times + searchsorted for current AND next stage (deterministic everywhere)
  {
    float tb = __fadd_rn(t0v, __fmul_rn((float)stepi, dtv));
    float t_cur, t_nxt;
    if constexpr (SIN == 0) t_cur = tb;
    else {
      constexpr float cS = (SIN == 1) ? 0.161f : (SIN == 2) ? 0.327f : (SIN == 3) ? 0.9f
                         : (SIN == 4) ? 0.9800255409045097f : 1.0f;
      t_cur = __fadd_rn(tb, __fmul_rn(cS, dtv));
    }
    if constexpr (SIN == 5) t_nxt = __fadd_rn(t0v, __fmul_rn((float)(stepi + 1), dtv));
    else {
      constexpr float cN = (SIN == 0) ? 0.161f : (SIN == 1) ? 0.327f : (SIN == 2) ? 0.9f
                         : (SIN == 3) ? 0.9800255409045097f : 1.0f;
      t_nxt = __fadd_rn(tb, __fmul_rn(cN, dtv));
    }
    if (tid < 64) {
      unsigned long long m1 = __ballot(intv[tid] < t_cur);
      unsigned long long m2 = __ballot(intv[tid] < t_nxt);
      if (tid == 0) { *sidxp = (int)__popcll(m1); *sidxnp = (int)__popcll(m2); }
    }
  }
  __syncthreads();
  const int idx = *sidxp, idxn = *sidxnp;
  const bool rebuild = (idx != last_idx);
  const bool rebuild_next = (idxn != idx);
  last_idx = idx;
  if (rebuild && g < 33) {  // blocks (h<33, Rg=0) scatter one 16-wide l stripe (rare)
    const int l0t = g * 16;
    const int part = tid & 3;
    #pragma unroll 1
    for (int bi = 0; bi < 4; ++bi) {
      const int b = bi * 128 + (tid >> 2);
      const float* srow = logsig + ((size_t)b * 65 + idx) * 529 + 1 + l0t + part * 4;
      #pragma unroll
      for (int c2 = 0; c2 < 4; ++c2)
        STOREC(&SGT[(size_t)(l0t + part * 4 + c2) * 512 + b], srow[c2]);
    }
  }
  // MLP for 2 rows (256 threads: row = tid>>7, j = tid&127)
  if (tid < 256) {
    const int row = tid >> 7, j = tid & 127;
    float acc = b0[j];
    const float4_* wr = (const float4_*)(w0 + (size_t)j * 64);
    #pragma unroll
    for (int i4 = 0; i4 < 16; ++i4) {
      float4_ wvv = wr[i4];
      acc = fmaf(yst[row][4*i4+0], wvv[0], acc);
      acc = fmaf(yst[row][4*i4+1], wvv[1], acc);
      acc = fmaf(yst[row][4*i4+2], wvv[2], acc);
      acc = fmaf(yst[row][4*i4+3], wvv[3], acc);
    }
    hb1[row][j] = fast_silu(acc);
  }
  __syncthreads();
  if (tid < 256) {
    const int row = tid >> 7, j = tid & 127;
    float acc = b1[j];
    const float4_* wr = (const float4_*)(w1 + (size_t)j * 128);
    #pragma unroll
    for (int i4 = 0; i4 < 32; ++i4) {
      float4_ wvv = wr[i4];
      acc = fmaf(hb1[row][4*i4+0], wvv[0], acc);
      acc = fmaf(hb1[row][4*i4+1], wvv[1], acc);
      acc = fmaf(hb1[row][4*i4+2], wvv[2], acc);
      acc = fmaf(hb1[row][4*i4+3], wvv[3], acc);
    }
    hb2[row][j] = fast_silu(acc);
  }
  __syncthreads();
  if (tid < 256) {
    const int row = tid >> 7, j = tid & 127;
    float acc = b2[j];
    const float4_* wr = (const float4_*)(w2 + (size_t)j * 128);
    #pragma unroll
    for (int i4 = 0; i4 < 32; ++i4) {
      float4_ wvv = wr[i4];
      acc = fmaf(hb2[row][4*i4+0], wvv[0], acc);
      acc = fmaf(hb2[row][4*i4+1], wvv[1], acc);
      acc = fmaf(hb2[row][4*i4+2], wvv[2], acc);
      acc = fmaf(hb2[row][4*i4+3], wvv[3], acc);
    }
    hdnS[row][j] = f2bf(fast_silu(acc));
  }
  __syncthreads();
  // pack-store hdn into A-fragment layout in WS (dword stores, coalesced-ish)
  if (tid < 128) {
    const int row = tid >> 6, u = tid & 63;
    const int lb = 2 * h + row;            // local row within Rg
    const int tile = lb >> 4, colp = lb & 15;
    const int j0 = 2 * u;
    const int kb = j0 >> 5, qdp = (j0 >> 3) & 3, jj = j0 & 7;
    unsigned v = (unsigned)hdnS[row][j0] | ((unsigned)hdnS[row][j0 + 1] << 16);
    unsigned i16 = (unsigned)((Rg * 32 + tile * 4 + kb) * 512 + qdp * 128 + colp * 8 + jj);
    STOREC(&HDNF[i16 >> 1], v);
  }
  // ---- barrier 1 (global only on rebuild stages, for SGT coherence) ----
  if (rebuild) {
    ++gseq; gridbar(BAR, g, gseq);
    __builtin_amdgcn_fence(__ATOMIC_ACQUIRE, "agent");  // invalidate stale cached SGT
  } else {
    ++rseq; rgbar(BAR, h, Rg, rseq);
  }

  // ---- phase 2: GEMM 128 x 528 x 128 (wave wv owns m-tile wv), no internal syncs ----
  {
    const unsigned long long* H64 = (const unsigned long long*)HDNF;
    union { unsigned long long u[2]; short8 s; } af[4];
    #pragma unroll
    for (int kb = 0; kb < 4; ++kb) {
      const unsigned i16 = (unsigned)((Rg * 32 + wv * 4 + kb) * 512 + lane * 8);
      af[kb].u[0] = LOADC(&H64[i16 >> 2]);
      af[kb].u[1] = LOADC(&H64[(i16 >> 2) + 1]);
    }
    float kp[4] = {0.0f, 0.0f, 0.0f, 0.0f};
    #pragma unroll 2
    for (int nt = 0; nt < 33; ++nt) {
      const int l = nt * 16 + col;
      const float bv = b3lds[l];
      float4_ acc; acc[0] = bv; acc[1] = bv; acc[2] = bv; acc[3] = bv;
      #pragma unroll
      for (int kb = 0; kb < 4; ++kb) {
        const short8 bf = *(const short8*)(w3lds + ((nt * 4 + kb) * 64 + lane) * 8);
        acc = __builtin_amdgcn_mfma_f32_16x16x32_bf16(af[kb].s, bf, acc, 0, 0, 0);
      }
      const float4_ s4 = *(const float4_*)(SGT + (size_t)l * 512 + R + wv * 16 + qd * 4);
      #pragma unroll
      for (int r = 0; r < 4; ++r)
        kp[r] = fmaf(fast_tanh(acc[r]), s4[r], kp[r]);
    }
    #pragma unroll
    for (int r = 0; r < 4; ++r) {
      float v = kp[r];
      v += __shfl_xor(v, 1); v += __shfl_xor(v, 2);
      v += __shfl_xor(v, 4); v += __shfl_xor(v, 8);
      kp[r] = v;
    }
    if (col == 0) {
      float* KFw = KF + (sg & 1) * 32768;
      #pragma unroll
      for (int r = 0; r < 4; ++r)
        STOREC(&KFw[(size_t)(R + wv * 16 + qd * 4 + r) * 64 + h], kp[r]);
    }
  }
  // ---- barrier 2 (global only if next stage rebuilds) ----
  if (rebuild_next) { ++gseq; gridbar(BAR, g, gseq); }
  else              { ++rseq; rgbar(BAR, h, Rg, rseq); }
}

__global__ void __launch_bounds__(NTHR, 2)
rde_kernel(const float* __restrict__ ts, const float* __restrict__ logsig,
           const float* __restrict__ x0, const float* __restrict__ intervals,
           const float* __restrict__ w0, const float* __restrict__ b0,
           const float* __restrict__ w1, const float* __restrict__ b1,
           const float* __restrict__ w2, const float* __restrict__ b2,
           const float* __restrict__ w3, const float* __restrict__ b3,
           const float* __restrict__ l1w, const float* __restrict__ l1b,
           const float* __restrict__ l2w, const float* __restrict__ l2b,
           float* out, unsigned char* ws) {
  const int tid = threadIdx.x;
  const int g = blockIdx.x;
  const int h = g & 63;          // owned head
  const int Rg = g >> 6;         // owned row-group
  const int R = Rg * 128;
  unsigned* BAR = (unsigned*)(ws + WS_BAR);
  unsigned gseq = 0, rseq = 0;
  int last_idx = -1;

  __shared__ __attribute__((aligned(16))) unsigned short w3lds[67584]; // 135.2 KB
  __shared__ float b3lds[528];
  __shared__ float intv[64];
  __shared__ float yst[2][64];
  __shared__ float hb1[2][128];
  __shared__ float hb2[2][128];
  __shared__ __attribute__((aligned(8))) unsigned short hdnS[2][128];
  __shared__ int sidx, sidxn;

  if (tid < 64) intv[tid] = intervals[tid];
  for (int e = tid; e < 528; e += NTHR) b3lds[e] = b3[(size_t)h * 528 + e];

  // w3 head-slice -> LDS bf16 B-fragments (once)
  for (int e = tid; e < 8448; e += NTHR) {   // 33 nt * 4 kb * 64 lanes
    const int ln = e & 63, kb = (e >> 6) & 3, nt = e >> 8;
    const float* src = w3 + ((size_t)(h * 528 + nt * 16 + (ln & 15))) * 128 + kb * 32 + (ln >> 4) * 8;
    union { unsigned short s[8]; short8 v; } p;
    #pragma unroll
    for (int j = 0; j < 8; ++j) p.s[j] = f2bf(src[j]);
    *(short8*)(w3lds + e * 8) = p.v;
  }

  // y0 = x0 @ l1w.T + l1b for own 2 rows (tid<128: row=tid>>6, hh=tid&63)
  float y = 0.0f, kh[6];
  #pragma unroll
  for (int i = 0; i < 6; ++i) kh[i] = 0.0f;
  if (tid < 128) {
    const int row = tid >> 6, hh = tid & 63;
    float acc = l1b[hh];
    const float4_* xr = (const float4_*)(x0 + (size_t)(2 * g + row) * 32);
    const float4_* wr = (const float4_*)(l1w + (size_t)hh * 32);
    #pragma unroll
    for (int d = 0; d < 8; ++d) {
      float4_ xv = xr[d], wvv = wr[d];
      acc = fmaf(xv[0], wvv[0], acc); acc = fmaf(xv[1], wvv[1], acc);
      acc = fmaf(xv[2], wvv[2], acc); acc = fmaf(xv[3], wvv[3], acc);
    }
    y = acc;
  }
  const float t0v = ts[0];
  const float dtv = (ts[128] - t0v) * (1.0f / 256.0f);
  __syncthreads();

  // ---- 256 steps x 6 stages ----
  for (int stepi = 0; stepi < 256; ++stepi) {
    const int sg = stepi * 6;
    rk_stage<0>(stepi, sg + 0, g, h, Rg, R, kh, y, t0v, dtv, ws, BAR, gseq, rseq, last_idx,
                logsig, w0, b0, w1, b1, w2, b2, w3lds, b3lds, intv, yst, hb1, hb2, hdnS, &sidx, &sidxn);
    rk_stage<1>(stepi, sg + 1, g, h, Rg, R, kh, y, t0v, dtv, ws, BAR, gseq, rseq, last_idx,
                logsig, w0, b0, w1, b1, w2, b2, w3lds, b3lds, intv, yst, hb1, hb2, hdnS, &sidx, &sidxn);
    rk_stage<2>(stepi, sg + 2, g, h, Rg, R, kh, y, t0v, dtv, ws, BAR, gseq, rseq, last_idx,
                logsig, w0, b0, w1, b1, w2, b2, w3lds, b3lds, intv, yst, hb1, hb2, hdnS, &sidx, &sidxn);
    rk_stage<3>(stepi, sg + 3, g, h, Rg, R, kh, y, t0v, dtv, ws, BAR, gseq, rseq, last_idx,
                logsig, w0, b0, w1, b1, w2, b2, w3lds, b3lds, intv, yst, hb1, hb2, hdnS, &sidx, &sidxn);
    rk_stage<4>(stepi, sg + 4, g, h, Rg, R, kh, y, t0v, dtv, ws, BAR, gseq, rseq, last_idx,
                logsig, w0, b0, w1, b1, w2, b2, w3lds, b3lds, intv, yst, hb1, hb2, hdnS, &sidx, &sidxn);
    rk_stage<5>(stepi, sg + 5, g, h, Rg, R, kh, y, t0v, dtv, ws, BAR, gseq, rseq, last_idx,
                logsig, w0, b0, w1, b1, w2, b2, w3lds, b3lds, intv, yst, hb1, hb2, hdnS, &sidx, &sidxn);
  }

  // ---- epilogue: ingest k6 of step 255, final y, head, softmax (own 2 rows) ----
  {
    float* KF = (float*)(ws + WS_KF);
    if (tid < 128) {
      const int row = tid >> 6, hh = tid & 63;
      kh[5] = LOADC(&KF[(size_t)32768 + (size_t)(2 * g + row) * 64 + hh]);  // sg=1535 parity 1
      y += dtv * (0.09646076681806523f * kh[0] + 0.01f * kh[1]
                + 0.4798896504144996f * kh[2] + 1.379008574103742f * kh[3]
                - 3.290069515436081f * kh[4] + 2.324710524099774f * kh[5]);
      yst[row][hh] = y;
    }
    __syncthreads();
    if (tid < 20) {
      const int row = tid / 10, c = tid % 10;
      float acc = l2b[c];
      const float* wr = l2w + c * 64;
      #pragma unroll
      for (int i2 = 0; i2 < 64; ++i2) acc = fmaf(yst[row][i2], wr[i2], acc);
      hb1[row][c] = acc;
    }
    __syncthreads();
    if (tid < 2) {
      const int row = tid;
      float mx = -1e30f;
      for (int c = 0; c < 10; ++c) mx = fmaxf(mx, hb1[row][c]);
      float ev[10], den = 0.0f;
      for (int c = 0; c < 10; ++c) { ev[c] = expf(hb1[row][c] - mx); den += ev[c]; }
      const float rd = 1.0f / den;
      for (int c = 0; c < 10; ++c) out[(size_t)(2 * g + row) * 10 + c] = ev[c] * rd;
    }
  }
}

extern "C" void kernel_launch(void* const* d_in, const int* in_sizes, int n_in,
                              void* d_out, int out_size, void* d_ws, size_t ws_size,
                              hipStream_t stream) {
  (void)in_sizes; (void)n_in; (void)out_size; (void)ws_size;
  const float* ts        = (const float*)d_in[0];
  const float* logsig    = (const float*)d_in[1];
  const float* x0        = (const float*)d_in[2];
  const float* intervals = (const float*)d_in[3];
  const float* w0        = (const float*)d_in[4];
  const float* b0        = (const float*)d_in[5];
  const float* w1        = (const float*)d_in[6];
  const float* b1        = (const float*)d_in[7];
  const float* w2        = (const float*)d_in[8];
  const float* b2        = (const float*)d_in[9];
  const float* w3        = (const float*)d_in[10];
  const float* b3        = (const float*)d_in[11];
  const float* l1w       = (const float*)d_in[12];
  const float* l1b       = (const float*)d_in[13];
  const float* l2w       = (const float*)d_in[14];
  const float* l2b       = (const float*)d_in[15];
  float* out = (float*)d_out;
  unsigned char* ws = (unsigned char*)d_ws;

  hipMemsetAsync(d_ws, 0, 12288, stream);  // zero all barrier counters

  void* args[] = { &ts, &logsig, &x0, &intervals, &w0, &b0, &w1, &b1,
                   &w2, &b2, &w3, &b3, &l1w, &l1b, &l2w, &l2b, &out, &ws };
  hipLaunchCooperativeKernel((void*)rde_kernel, dim3(NBLK), dim3(NTHR), args, 0, stream);
}